// Round 1
// baseline (536.831 us; speedup 1.0000x reference)
//
#include <hip/hip_runtime.h>

#define M_DIM 8192
#define N_DIM 4096
#define K_DIM 4096

typedef _Float16 f16;
typedef _Float16 f16x8 __attribute__((ext_vector_type(8)));
typedef float f32x16 __attribute__((ext_vector_type(16)));

// async global->LDS, 16B per lane. LDS dest is wave-uniform base; HW stores lane i at base + i*16.
__device__ __forceinline__ void lds_async16(void* lds, const void* g) {
    __builtin_amdgcn_global_load_lds(
        (const __attribute__((address_space(1))) void*)(void*)g,
        (__attribute__((address_space(3))) void*)lds, 16, 0, 0);
}

// ---- prepass: fp32 x -> f16 (8 floats / thread) ----
__global__ __launch_bounds__(256) void cvt_x_kernel(const float* __restrict__ x, f16* __restrict__ xh) {
    size_t idx  = (size_t)blockIdx.x * 256 + threadIdx.x;
    size_t base = idx * 8;
    const float4* xp = (const float4*)(x + base);
    float4 v0 = xp[0], v1 = xp[1];
    f16x8 h;
    h[0] = (f16)v0.x; h[1] = (f16)v0.y; h[2] = (f16)v0.z; h[3] = (f16)v0.w;
    h[4] = (f16)v1.x; h[5] = (f16)v1.y; h[6] = (f16)v1.z; h[7] = (f16)v1.w;
    *(f16x8*)(xh + base) = h;
}

// ---- prepass: packed int4 (one byte per int32, hi nibble first) -> f16 Q in [-8,7] ----
__global__ __launch_bounds__(256) void cvt_w_kernel(const int* __restrict__ pw, f16* __restrict__ wh) {
    size_t idx = (size_t)blockIdx.x * 256 + threadIdx.x;  // 4 ints / thread -> 8 halves
    int4 v = ((const int4*)pw)[idx];
    f16x8 h;
    int a;
    a = v.x; h[0] = (f16)(((a >> 4) & 15) - 8); h[1] = (f16)((a & 15) - 8);
    a = v.y; h[2] = (f16)(((a >> 4) & 15) - 8); h[3] = (f16)((a & 15) - 8);
    a = v.z; h[4] = (f16)(((a >> 4) & 15) - 8); h[5] = (f16)((a & 15) - 8);
    a = v.w; h[6] = (f16)(((a >> 4) & 15) - 8); h[7] = (f16)((a & 15) - 8);
    *(f16x8*)(wh + idx * 8) = h;
}

// ---- main GEMM: C[M,N] = sw * (A[M,K] @ B[N,K]^T) + bias[N] ----
// 256x256 tile, 8 waves (2M x 4N), per-wave 128x64 (4mt x 2nt of 32x32), BK=64.
// Double-buffered LDS (128 KiB). Per K-tile: 4 phases (one per K=16 MFMA step);
// each phase: 6 ds_read_b128 + 2 global_load_lds (K-half staging unit of next tile)
// + barrier + lgkmcnt(0) + 8 MFMA + barrier. vmcnt(4) twice per tile, never 0.
//
// LDS buffer (32 KB, per operand): [khalf h][chunk 0..31][512B].
// chunk = 8 rows x 32 halves; slot(rr,kc2) = rr*4 + ((kc2 ^ (rr>>1)) & 3)  (kc2 = 16B unit 0..3)
// -> each 8-lane ds_read_b128 group covers all 8 distinct 4-bank groups: conflict-free.
// Staging (linear dest, inverse-swizzled source): lane i of a 1KB unit-instr:
//   row += (i>>5)*8 + ((i>>2)&7);  k += ((i&3) ^ ((i>>3)&3)) * 8 halves.

#define PHASE(AC, BC, KK, STAGE_STMT, VM_STMT) do {                                              \
    const int h_   = (KK) >> 1;                                                                  \
    const int kc2_ = ((KK) & 1) * 2 + half;                                                      \
    f16x8 af0 = *(const f16x8*)&(AC)[h_ * 8192 + aoff[0] + ((kc2_ ^ axr[0]) << 3)];              \
    f16x8 af1 = *(const f16x8*)&(AC)[h_ * 8192 + aoff[1] + ((kc2_ ^ axr[1]) << 3)];              \
    f16x8 af2 = *(const f16x8*)&(AC)[h_ * 8192 + aoff[2] + ((kc2_ ^ axr[2]) << 3)];              \
    f16x8 af3 = *(const f16x8*)&(AC)[h_ * 8192 + aoff[3] + ((kc2_ ^ axr[3]) << 3)];              \
    f16x8 bf0 = *(const f16x8*)&(BC)[h_ * 8192 + boff[0] + ((kc2_ ^ bxr[0]) << 3)];              \
    f16x8 bf1 = *(const f16x8*)&(BC)[h_ * 8192 + boff[1] + ((kc2_ ^ bxr[1]) << 3)];              \
    STAGE_STMT;                                                                                  \
    __builtin_amdgcn_s_barrier();                                                                \
    asm volatile("s_waitcnt lgkmcnt(0)" ::: "memory");                                           \
    __builtin_amdgcn_sched_barrier(0);                                                           \
    __builtin_amdgcn_s_setprio(1);                                                               \
    acc[0][0] = __builtin_amdgcn_mfma_f32_32x32x16_f16(af0, bf0, acc[0][0], 0, 0, 0);            \
    acc[0][1] = __builtin_amdgcn_mfma_f32_32x32x16_f16(af0, bf1, acc[0][1], 0, 0, 0);            \
    acc[1][0] = __builtin_amdgcn_mfma_f32_32x32x16_f16(af1, bf0, acc[1][0], 0, 0, 0);            \
    acc[1][1] = __builtin_amdgcn_mfma_f32_32x32x16_f16(af1, bf1, acc[1][1], 0, 0, 0);            \
    acc[2][0] = __builtin_amdgcn_mfma_f32_32x32x16_f16(af2, bf0, acc[2][0], 0, 0, 0);            \
    acc[2][1] = __builtin_amdgcn_mfma_f32_32x32x16_f16(af2, bf1, acc[2][1], 0, 0, 0);            \
    acc[3][0] = __builtin_amdgcn_mfma_f32_32x32x16_f16(af3, bf0, acc[3][0], 0, 0, 0);            \
    acc[3][1] = __builtin_amdgcn_mfma_f32_32x32x16_f16(af3, bf1, acc[3][1], 0, 0, 0);            \
    __builtin_amdgcn_s_setprio(0);                                                               \
    VM_STMT;                                                                                     \
    __builtin_amdgcn_s_barrier();                                                                \
} while (0)

// K-tile step: phases kk=0..3 reading (AC,BC); staging units of tile T+1 into (AN,BN)
// in issue order A-h0, B-h0, A-h1, B-h1 (2 loads each).
#define TILE_STEP(AC, BC, AN, BN, T) do {                                                        \
    const int kn_ = ((T) < 63) ? ((T) + 1) * 64 : 63 * 64;  /* last-tile prefetch: safe dummy */ \
    PHASE(AC, BC, 0,                                                                             \
          { lds_async16(&(AN)[dA0], aSrc[0] + kn_); lds_async16(&(AN)[dA1], aSrc[1] + kn_); },   \
          );                                                                                     \
    PHASE(AC, BC, 1,                                                                             \
          { lds_async16(&(BN)[dA0], bSrc[0] + kn_); lds_async16(&(BN)[dA1], bSrc[1] + kn_); },   \
          asm volatile("s_waitcnt vmcnt(4)" ::: "memory"));                                      \
    PHASE(AC, BC, 2,                                                                             \
          { lds_async16(&(AN)[8192 + dA0], aSrc[0] + kn_ + 32);                                  \
            lds_async16(&(AN)[8192 + dA1], aSrc[1] + kn_ + 32); },                               \
          );                                                                                     \
    PHASE(AC, BC, 3,                                                                             \
          { lds_async16(&(BN)[8192 + dA0], bSrc[0] + kn_ + 32);                                  \
            lds_async16(&(BN)[8192 + dA1], bSrc[1] + kn_ + 32); },                               \
          asm volatile("s_waitcnt vmcnt(4)" ::: "memory"));                                      \
} while (0)

__global__ __launch_bounds__(512, 2) void gemm_f16(const f16* __restrict__ A, const f16* __restrict__ B,
                                                   const int* __restrict__ pb,
                                                   const float* __restrict__ psw, const float* __restrict__ psb,
                                                   float* __restrict__ out) {
    __shared__ f16 As[2][16384];   // 2 x 32 KB
    __shared__ f16 Bs[2][16384];   // 2 x 32 KB

    const int tid  = threadIdx.x;
    const int wave = tid >> 6;
    const int lane = tid & 63;
    const int l32  = lane & 31;
    const int half = lane >> 5;
    const int wm   = wave >> 2;          // 2 x 4 waves of 128x64
    const int wn   = wave & 3;

    // XCD-bijective block swizzle: 512 wgs, 8 XCDs, 64 per XCD
    const int bid = blockIdx.x;
    const int swz = (bid & 7) * 64 + (bid >> 3);
    const int bx  = swz & 15;            // N tiles: 16
    const int by  = swz >> 4;            // M tiles: 32
    const int mbase = by * 256;
    const int nbase = bx * 256;

    // ---- staging source addresses (inverse-swizzled; dest is linear lane*16B) ----
    const int rL   = ((lane >> 5) & 1) * 8 + ((lane >> 2) & 7);      // row within 16-row unit-instr
    const int kswz = (((lane & 3) ^ ((lane >> 3) & 3))) * 8;          // k offset (halves) within 32
    const f16* aSrc[2]; const f16* bSrc[2];
#pragma unroll
    for (int j = 0; j < 2; j++) {
        aSrc[j] = A + (size_t)(mbase + j * 128 + wave * 16 + rL) * K_DIM + kswz;
        bSrc[j] = B + (size_t)(nbase + j * 128 + wave * 16 + rL) * K_DIM + kswz;
    }
    const int dA0 = wave * 512;          // LDS dest (halves) for j=0 unit-instr
    const int dA1 = 4096 + wave * 512;   // j=1

    // ---- fragment read bases (halves): chunk*256 + rr*32; xor term (rr>>1)&3 ----
    int aoff[4], axr[4];
#pragma unroll
    for (int mt = 0; mt < 4; mt++) {
        int ra = wm * 128 + mt * 32 + l32;
        aoff[mt] = (ra >> 3) * 256 + (ra & 7) * 32;
        axr[mt]  = ((ra & 7) >> 1) & 3;
    }
    int boff[2], bxr[2];
#pragma unroll
    for (int nt = 0; nt < 2; nt++) {
        int rb = wn * 64 + nt * 32 + l32;
        boff[nt] = (rb >> 3) * 256 + (rb & 7) * 32;
        bxr[nt]  = ((rb & 7) >> 1) & 3;
    }

    f32x16 acc[4][2] = {};

    // ---- prologue: stage tile 0 into buf 0 (issue order A-h0, B-h0, A-h1, B-h1) ----
    lds_async16(&As[0][dA0], aSrc[0]);
    lds_async16(&As[0][dA1], aSrc[1]);
    lds_async16(&Bs[0][dA0], bSrc[0]);
    lds_async16(&Bs[0][dA1], bSrc[1]);
    lds_async16(&As[0][8192 + dA0], aSrc[0] + 32);
    lds_async16(&As[0][8192 + dA1], aSrc[1] + 32);
    lds_async16(&Bs[0][8192 + dA0], bSrc[0] + 32);
    lds_async16(&Bs[0][8192 + dA1], bSrc[1] + 32);
    asm volatile("s_waitcnt vmcnt(4)" ::: "memory");   // A-h0,B-h0 of tile 0 landed
    __builtin_amdgcn_s_barrier();

#pragma unroll 1
    for (int t = 0; t < 64; t += 2) {
        TILE_STEP(As[0], Bs[0], As[1], Bs[1], t);
        TILE_STEP(As[1], Bs[1], As[0], Bs[0], t + 1);
    }

    // drain trailing dummy prefetch before LDS deallocation at endpgm
    asm volatile("s_waitcnt vmcnt(0)" ::: "memory");

    const float sw = *psw;
    const float sb = *psb;

    // C/D layout (m74/m101): col = lane&31, row = (reg&3) + 8*(reg>>2) + 4*(lane>>5)
#pragma unroll
    for (int nt = 0; nt < 2; nt++) {
        const int gcol = nbase + wn * 64 + nt * 32 + l32;
        const int p    = pb[gcol >> 1];
        const int nib  = (gcol & 1) ? (p & 15) : ((p >> 4) & 15);
        const float bias = sb * (float)(nib - 8);
#pragma unroll
        for (int mt = 0; mt < 4; mt++) {
            const int rbase = mbase + wm * 128 + mt * 32 + half * 4;
#pragma unroll
            for (int g = 0; g < 4; g++) {
                float* o = out + (size_t)(rbase + g * 8) * N_DIM + gcol;
#pragma unroll
                for (int r = 0; r < 4; r++)
                    o[(size_t)r * N_DIM] = sw * acc[mt][nt][g * 4 + r] + bias;
            }
        }
    }
}

// ---- correct-but-slow fallback if workspace is too small for the f16 copies ----
__global__ __launch_bounds__(256) void gemm_fallback(const float* __restrict__ x, const int* __restrict__ pw,
                                                     const int* __restrict__ pb,
                                                     const float* __restrict__ psw, const float* __restrict__ psb,
                                                     float* __restrict__ out) {
    __shared__ float As[16][17];
    __shared__ float Bs[16][17];
    const int tx = threadIdx.x & 15, ty = threadIdx.x >> 4;
    const int row = blockIdx.y * 16 + ty;   // m
    const int col = blockIdx.x * 16 + tx;   // n
    float acc = 0.f;
    for (int k0 = 0; k0 < K_DIM; k0 += 16) {
        As[ty][tx] = x[(size_t)row * K_DIM + k0 + tx];
        const int nrow = blockIdx.x * 16 + ty;
        const int k = k0 + tx;
        const int p = pw[((size_t)nrow * K_DIM + k) >> 1];
        const int nib = (k & 1) ? (p & 15) : ((p >> 4) & 15);
        Bs[ty][tx] = (float)(nib - 8);
        __syncthreads();
#pragma unroll
        for (int kk = 0; kk < 16; kk++)
            acc += As[ty][kk] * Bs[tx][kk];
        __syncthreads();
    }
    const float sw = *psw, sb = *psb;
    const int p = pb[col >> 1];
    const int nib = (col & 1) ? (p & 15) : ((p >> 4) & 15);
    out[(size_t)row * N_DIM + col] = sw * acc + sb * (float)(nib - 8);
}

extern "C" void kernel_launch(void* const* d_in, const int* in_sizes, int n_in,
                              void* d_out, int out_size, void* d_ws, size_t ws_size,
                              hipStream_t stream) {
    (void)in_sizes; (void)n_in; (void)out_size;
    const float* x   = (const float*)d_in[0];
    const int*   pw  = (const int*)d_in[1];
    const int*   pb  = (const int*)d_in[2];
    const float* psw = (const float*)d_in[3];
    const float* psb = (const float*)d_in[4];
    float* out = (float*)d_out;

    const size_t xh_bytes = (size_t)M_DIM * K_DIM * sizeof(f16);   // 67.1 MB
    const size_t wh_bytes = (size_t)N_DIM * K_DIM * sizeof(f16);   // 33.6 MB

    if (ws_size >= xh_bytes + wh_bytes) {
        f16* xh = (f16*)d_ws;
        f16* wh = (f16*)((char*)d_ws + xh_bytes);
        cvt_x_kernel<<<(M_DIM * (size_t)K_DIM) / 8 / 256, 256, 0, stream>>>(x, xh);
        cvt_w_kernel<<<((size_t)N_DIM * K_DIM / 2) / 4 / 256, 256, 0, stream>>>(pw, wh);
        gemm_f16<<<dim3((M_DIM / 256) * (N_DIM / 256)), 512, 0, stream>>>(xh, wh, pb, psw, psb, out);
    } else {
        gemm_fallback<<<dim3(N_DIM / 16, M_DIM / 16), 256, 0, stream>>>(x, pw, pb, psw, psb, out);
    }
}